// Round 2
// baseline (155.820 us; speedup 1.0000x reference)
//
#include <hip/hip_runtime.h>

// ECT: out[b,c,r,t] = sum_{n in (b,c)} sigmoid(SCALE*(lin[r] - x[n].v[:,t])), max-normalized per (b,c).
// Window trick: sigmoid saturates within +-3 bins (SCALE=100, bin=2/63) -> compute 6 exact bins
// per point, histogram the "+1 for all r >= lo+6" tail, prefix-sum over r at the end.

constexpr int T   = 64;
constexpr int RES = 64;
constexpr float RADIUS = 1.0f;
constexpr float SCALE  = 100.0f;
constexpr float LOG2E  = 1.44269504088896340736f;

#define THREADS 1024
#define WAVES   16
#define CHUNK   1024
#define NB      6       // exact-sigmoid window bins
#define WIN     3.0f    // window half-width in bin units

__global__ __launch_bounds__(THREADS) void ect_main(
    const float* __restrict__ x, const float* __restrict__ v,
    const int* __restrict__ index, const int* __restrict__ channels,
    float* __restrict__ out, int N)
{
  __shared__ float    lx[CHUNK * 4];     // compacted points, float4-padded (16KB)
  __shared__ float    sig[T * 65];       // exact-window accumulator [t][r], padded (16.6KB)
  __shared__ unsigned hist[T * 66];      // tail histogram [t][0..64], padded (16.9KB)
  __shared__ float    fin[RES * T];      // final [r][t] (16KB)
  __shared__ int      l_bounds[2];
  __shared__ int      l_cnt;
  __shared__ float    wmax[WAVES];
  __shared__ float    s_scale;

  const int seg  = blockIdx.x;
  const int b    = seg >> 2;     // MAX_CHANNELS == 4
  const int c    = seg & 3;
  const int tid  = threadIdx.x;
  const int lane = tid & 63;
  const int wv   = tid >> 6;

  // zero LDS accumulators
  for (int i = tid; i < T * 65; i += THREADS) sig[i]  = 0.0f;
  for (int i = tid; i < T * 66; i += THREADS) hist[i] = 0u;

  // batch bounds via binary search (index sorted)
  if (tid < 2) {
    int target = b + tid, lo = 0, hi = N;
    while (lo < hi) { int mid = (lo + hi) >> 1; if (index[mid] < target) lo = mid + 1; else hi = mid; }
    l_bounds[tid] = lo;
  }
  __syncthreads();
  const int s0 = l_bounds[0], s1 = l_bounds[1];

  // per-lane direction t = lane
  const float v0 = v[0 * T + lane], v1 = v[1 * T + lane], v2 = v[2 * T + lane];
  const float S2   = SCALE * LOG2E;                    // 144.2695
  const float S2D  = S2 * (2.0f * RADIUS / (RES - 1)); // arg step per bin
  const float invD = (RES - 1) / (2.0f * RADIUS);      // 31.5

  for (int base = s0; base < s1; base += CHUNK) {
    const int cnt = min(CHUNK, s1 - base);
    if (tid == 0) l_cnt = 0;
    __syncthreads();
    // ballot-compact channel-c points into lx
    if (tid < cnt) {
      const int pt = base + tid;
      const bool match = (channels[pt] == c);
      unsigned long long mask = __ballot(match);
      int wcnt = __popcll(mask);
      int pos = 0;
      if (lane == 0 && wcnt) pos = atomicAdd(&l_cnt, wcnt);
      pos = __shfl(pos, 0);
      if (match) {
        int off = pos + __popcll(mask & ((1ull << lane) - 1ull));
        lx[off * 4 + 0] = x[pt * 3 + 0];
        lx[off * 4 + 1] = x[pt * 3 + 1];
        lx[off * 4 + 2] = x[pt * 3 + 2];
      }
    }
    __syncthreads();
    const int m = l_cnt;

    // waves stripe points; all 64 lanes (=64 t's) process each point
    for (int j = wv; j < m; j += WAVES) {
      const float4 p  = *reinterpret_cast<const float4*>(&lx[j * 4]);
      const float  nh = p.x * v0 + p.y * v1 + p.z * v2;
      const float  B  = S2 * (1.0f + nh);
      // first window bin: lo = ceil((nh+1)*31.5 - 3)
      const float rf0 = ceilf(fmaf(nh + RADIUS, invD, -WIN));
      const int   lo  = (int)rf0;
      #pragma unroll
      for (int u = 0; u < NB; ++u) {
        // sigmoid(SCALE*(lin_r - nh)) = 1/(1 + 2^(B - r*S2D))
        float e   = __builtin_amdgcn_exp2f(fmaf(rf0 + (float)u, -S2D, B));
        float s   = __builtin_amdgcn_rcpf(1.0f + e);
        int   r   = lo + u;
        float val = ((unsigned)r < (unsigned)RES) ? s : 0.0f;
        int   rc  = min(max(r, 0), RES - 1);
        atomicAdd(&sig[lane * 65 + rc], val);
      }
      int ci = min(max(lo + NB, 0), RES);
      atomicAdd(&hist[lane * 66 + ci], 1u);   // +1 for all r >= ci
    }
  }
  __syncthreads();

  // per-t inclusive prefix over r of hist, combine with exact window sums
  #pragma unroll
  for (int u2 = 0; u2 < 4; ++u2) {
    const int t = (wv << 2) | u2;
    unsigned h = hist[t * 66 + lane];         // lane = r
    #pragma unroll
    for (int d = 1; d < 64; d <<= 1) {
      unsigned o = __shfl_up(h, (unsigned)d);
      if (lane >= d) h += o;
    }
    fin[lane * T + t] = sig[t * 65 + lane] + (float)h;
  }
  __syncthreads();

  // block max-reduce + normalize + store (coalesced)
  float vals[4];
  float mx = 0.0f;
  #pragma unroll
  for (int k = 0; k < 4; ++k) { vals[k] = fin[tid + k * THREADS]; mx = fmaxf(mx, vals[k]); }
  #pragma unroll
  for (int s = 32; s >= 1; s >>= 1) mx = fmaxf(mx, __shfl_xor(mx, s));
  if (lane == 0) wmax[wv] = mx;
  __syncthreads();
  if (tid == 0) {
    float m2 = wmax[0];
    #pragma unroll
    for (int i = 1; i < WAVES; ++i) m2 = fmaxf(m2, wmax[i]);
    s_scale = (m2 > 0.0f) ? 1.0f / m2 : 1.0f;
  }
  __syncthreads();
  const float sc = s_scale;
  float* o = out + (size_t)seg * (RES * T);
  #pragma unroll
  for (int k = 0; k < 4; ++k) o[tid + k * THREADS] = vals[k] * sc;
}

extern "C" void kernel_launch(void* const* d_in, const int* in_sizes, int n_in,
                              void* d_out, int out_size, void* d_ws, size_t ws_size,
                              hipStream_t stream) {
  const float* x        = (const float*)d_in[0];
  const float* v        = (const float*)d_in[1];
  const int*   index    = (const int*)d_in[2];
  const int*   channels = (const int*)d_in[3];
  float*       out      = (float*)d_out;
  const int N    = in_sizes[2];              // 32768
  const int nseg = out_size / (RES * T);     // 128

  hipLaunchKernelGGL(ect_main, dim3(nseg), dim3(THREADS), 0, stream,
                     x, v, index, channels, out, N);
}

// Round 3
// 22.677 us; speedup vs baseline: 6.8714x; 6.8714x over previous
//
#include <hip/hip_runtime.h>

// ECT: out[b,c,r,t] = sum_{n in (b,c)} sigmoid(SCALE*(lin[r] - x[n].v[:,t])), max-normalized per (b,c).
// Window trick: sigmoid saturates within +-3 bins (SCALE=100, bin=2/63) -> 6 exact bins per point,
// "+1 for all r >= lo+6" tail histogram, prefix-sum over r at the end.
// Accumulate in FIXED-POINT u32 (native ds_add_u32) — float LDS atomicAdd is a CAS loop (round-1 regression).

constexpr int T   = 64;
constexpr int RES = 64;
constexpr float RADIUS = 1.0f;
constexpr float SCALE  = 100.0f;
constexpr float LOG2E  = 1.44269504088896340736f;

#define THREADS 1024
#define WAVES   16
#define CHUNK   1024
#define NB      6                 // exact-sigmoid window bins
#define WIN     3.0f              // window half-width in bins
#define FPSCALE 1048576.0f        // 2^20 fixed-point scale
#define FPINV   (1.0f / 1048576.0f)

__global__ __launch_bounds__(THREADS) void ect_main(
    const float* __restrict__ x, const float* __restrict__ v,
    const int* __restrict__ index, const int* __restrict__ channels,
    float* __restrict__ out, int N)
{
  __shared__ float    lx[CHUNK * 4];     // compacted points, float4-padded
  __shared__ unsigned sig[T * 65];       // fixed-point exact-window accumulator [t][r], padded
  __shared__ unsigned hist[T * 66];      // tail histogram [t][0..64], padded
  __shared__ float    fin[RES * T];      // final [r][t]
  __shared__ int      l_bounds[2];
  __shared__ int      l_cnt;
  __shared__ float    wmax[WAVES];
  __shared__ float    s_scale;

  const int seg  = blockIdx.x;
  const int b    = seg >> 2;     // MAX_CHANNELS == 4
  const int c    = seg & 3;
  const int tid  = threadIdx.x;
  const int lane = tid & 63;
  const int wv   = tid >> 6;

  for (int i = tid; i < T * 65; i += THREADS) sig[i]  = 0u;
  for (int i = tid; i < T * 66; i += THREADS) hist[i] = 0u;

  // batch bounds via binary search (index sorted)
  if (tid < 2) {
    int target = b + tid, lo = 0, hi = N;
    while (lo < hi) { int mid = (lo + hi) >> 1; if (index[mid] < target) lo = mid + 1; else hi = mid; }
    l_bounds[tid] = lo;
  }
  __syncthreads();
  const int s0 = l_bounds[0], s1 = l_bounds[1];

  // per-lane direction t = lane
  const float v0 = v[0 * T + lane], v1 = v[1 * T + lane], v2 = v[2 * T + lane];
  const float S2   = SCALE * LOG2E;                    // 144.2695
  const float S2D  = S2 * (2.0f * RADIUS / (RES - 1)); // arg step per bin
  const float invD = (RES - 1) / (2.0f * RADIUS);      // 31.5
  const float QMUL = __builtin_amdgcn_exp2f(-S2D);     // per-bin decay of e

  for (int base = s0; base < s1; base += CHUNK) {
    const int cnt = min(CHUNK, s1 - base);
    if (tid == 0) l_cnt = 0;
    __syncthreads();
    // ballot-compact channel-c points into lx
    if (tid < cnt) {
      const int pt = base + tid;
      const bool match = (channels[pt] == c);
      unsigned long long mask = __ballot(match);
      int wcnt = __popcll(mask);
      int pos = 0;
      if (lane == 0 && wcnt) pos = atomicAdd(&l_cnt, wcnt);
      pos = __shfl(pos, 0);
      if (match) {
        int off = pos + __popcll(mask & ((1ull << lane) - 1ull));
        lx[off * 4 + 0] = x[pt * 3 + 0];
        lx[off * 4 + 1] = x[pt * 3 + 1];
        lx[off * 4 + 2] = x[pt * 3 + 2];
      }
    }
    __syncthreads();
    const int m = l_cnt;

    // waves stripe points; lane = t
    for (int j = wv; j < m; j += WAVES) {
      const float4 p  = *reinterpret_cast<const float4*>(&lx[j * 4]);
      const float  nh = p.x * v0 + p.y * v1 + p.z * v2;
      const float  B  = S2 * (RADIUS + nh);                 // arg(r) = B - r*S2D
      const float  rf0 = ceilf(fmaf(nh + RADIUS, invD, -WIN));
      const int    lo  = (int)rf0;
      // e0 = 2^(B - rf0*S2D) in (2^9.2, 2^13.8]; walk window via e *= 2^-S2D
      float e = __builtin_amdgcn_exp2f(fmaf(rf0, -S2D, B));
      #pragma unroll
      for (int u = 0; u < NB; ++u) {
        float s = __builtin_amdgcn_rcpf(1.0f + e);
        int   r = lo + u;
        unsigned q = ((unsigned)r < (unsigned)RES) ? (unsigned)fmaf(s, FPSCALE, 0.5f) : 0u;
        int   rc = min(max(r, 0), RES - 1);
        atomicAdd(&sig[lane * 65 + rc], q);   // native ds_add_u32
        e *= QMUL;
      }
      int ci = min(max(lo + NB, 0), RES);
      atomicAdd(&hist[lane * 66 + ci], 1u);   // +1 for all r >= ci
    }
  }
  __syncthreads();

  // per-t inclusive prefix over r of hist, combine with window sums
  #pragma unroll
  for (int u2 = 0; u2 < 4; ++u2) {
    const int t = (wv << 2) | u2;
    unsigned h = hist[t * 66 + lane];         // lane = r
    #pragma unroll
    for (int d = 1; d < 64; d <<= 1) {
      unsigned o = __shfl_up(h, (unsigned)d);
      if (lane >= d) h += o;
    }
    fin[lane * T + t] = (float)sig[t * 65 + lane] * FPINV + (float)h;
  }
  __syncthreads();

  // block max-reduce + normalize + store (coalesced)
  float vals[4];
  float mx = 0.0f;
  #pragma unroll
  for (int k = 0; k < 4; ++k) { vals[k] = fin[tid + k * THREADS]; mx = fmaxf(mx, vals[k]); }
  #pragma unroll
  for (int s = 32; s >= 1; s >>= 1) mx = fmaxf(mx, __shfl_xor(mx, s));
  if (lane == 0) wmax[wv] = mx;
  __syncthreads();
  if (tid == 0) {
    float m2 = wmax[0];
    #pragma unroll
    for (int i = 1; i < WAVES; ++i) m2 = fmaxf(m2, wmax[i]);
    s_scale = (m2 > 0.0f) ? 1.0f / m2 : 1.0f;
  }
  __syncthreads();
  const float sc = s_scale;
  float* o = out + (size_t)seg * (RES * T);
  #pragma unroll
  for (int k = 0; k < 4; ++k) o[tid + k * THREADS] = vals[k] * sc;
}

extern "C" void kernel_launch(void* const* d_in, const int* in_sizes, int n_in,
                              void* d_out, int out_size, void* d_ws, size_t ws_size,
                              hipStream_t stream) {
  const float* x        = (const float*)d_in[0];
  const float* v        = (const float*)d_in[1];
  const int*   index    = (const int*)d_in[2];
  const int*   channels = (const int*)d_in[3];
  float*       out      = (float*)d_out;
  const int N    = in_sizes[2];              // 32768
  const int nseg = out_size / (RES * T);     // 128

  hipLaunchKernelGGL(ect_main, dim3(nseg), dim3(THREADS), 0, stream,
                     x, v, index, channels, out, N);
}

// Round 4
// 18.127 us; speedup vs baseline: 8.5961x; 1.2510x over previous
//
#include <hip/hip_runtime.h>

// ECT: out[b,c,r,t] = sum_{n in (b,c)} sigmoid(SCALE*(lin[r] - x[n].v[:,t])), max-normalized per (b,c).
// Window trick: sigmoid saturates within +-2..3 bins (SCALE=100, bin=2/63). Per point: 4 exact bins
// from a precomputed LDS table (indexed by fractional bin position of nh), "+1 for all r >= lo+4"
// tail histogram, prefix-sum over r at the end. All accumulation in fixed-point u32 (native ds_add_u32).

constexpr int T   = 64;
constexpr int RES = 64;
constexpr float RADIUS = 1.0f;
constexpr float SCALE  = 100.0f;
constexpr float LOG2E  = 1.44269504088896340736f;

#define THREADS 1024
#define WAVES   16
#define CHUNK   1024
#define NB      4                  // exact window bins
#define PAD     5                  // sig index = r + PAD, r in [-5, 68] -> 74 slots (stride 75, odd)
#define SSTR    75
#define HSTR    66
#define TK      512                // table rows (fractional-position quantization)
#define FPSCALE 1048576.0f         // 2^20
#define FPINV   (1.0f / 1048576.0f)

__global__ __launch_bounds__(THREADS) void ect_main(
    const float* __restrict__ x, const float* __restrict__ v,
    const int* __restrict__ index, const int* __restrict__ channels,
    float* __restrict__ out, int N)
{
  __shared__ alignas(16) float    lx[4160];        // compacted points (CHUNK*float4) / reused as fin[64][65]
  __shared__ alignas(16) unsigned tbl[TK * NB];    // quantized sigmoid window table (8KB)
  __shared__ unsigned sig[T * SSTR];               // fixed-point window accumulator [t][r+PAD]
  __shared__ unsigned hist[T * HSTR];              // tail histogram [t][0..64]
  __shared__ int      l_bounds[2];
  __shared__ int      l_cnt;
  __shared__ float    wmax[WAVES];
  __shared__ float    s_scale;

  const int seg  = blockIdx.x;
  const int b    = seg >> 2;     // MAX_CHANNELS == 4
  const int c    = seg & 3;
  const int tid  = threadIdx.x;
  const int lane = tid & 63;
  const int wv   = tid >> 6;

  const float S2D  = SCALE * LOG2E * (2.0f * RADIUS / (RES - 1));  // log2-domain arg step per bin
  const float invD = (RES - 1) / (2.0f * RADIUS);                  // 31.5

  // zero accumulators
  for (int i = tid; i < T * SSTR; i += THREADS) sig[i]  = 0u;
  for (int i = tid; i < T * HSTR; i += THREADS) hist[i] = 0u;

  // build window table: tbl[q][u] = round(FPSCALE * sigmoid_nat(SCALE*binw*((u-1) - f))), f=(q+0.5)/TK
  for (int i = tid; i < TK * NB; i += THREADS) {
    int   q = i >> 2, u = i & 3;
    float f = (q + 0.5f) * (1.0f / TK);
    float e = __builtin_amdgcn_exp2f(S2D * (1.0f + f - (float)u));   // e^{-z} in log2 domain
    float s = 1.0f / (1.0f + e);
    tbl[i] = (unsigned)(s * FPSCALE + 0.5f);
  }

  // wave-parallel 64-ary search for batch bounds (waves 14,15; others proceed to barrier)
  if (wv >= 14) {
    const int tg = b + (wv - 14);
    int lo = 0, len = N;
    while (len > 64) {
      int step = (len + 63) >> 6;
      int p = lo + lane * step;
      bool lt = (p < lo + len) && (index[p] < tg);
      unsigned long long mask = __ballot(lt);
      if (mask != 0ull) {
        int h = 63 - __clzll(mask);
        lo = lo + h * step + 1;
      }
      len = step;
      len = min(len, N - lo);
    }
    int p = lo + lane;
    bool ge = (lane < len) && (index[p] >= tg);
    unsigned long long mask = __ballot(ge);
    int ans = mask ? (lo + (int)__builtin_ctzll(mask)) : (lo + len);
    if (lane == 0) l_bounds[wv - 14] = ans;
  }
  __syncthreads();
  const int s0 = l_bounds[0], s1 = l_bounds[1];

  // per-lane direction t = lane
  const float v0 = v[0 * T + lane], v1 = v[1 * T + lane], v2 = v[2 * T + lane];
  unsigned* const srow0 = &sig[lane * SSTR];
  unsigned* const hrow0 = &hist[lane * HSTR];

  for (int base = s0; base < s1; base += CHUNK) {
    const int cnt = min(CHUNK, s1 - base);
    if (tid == 0) l_cnt = 0;
    __syncthreads();
    // ballot-compact channel-c points into lx
    if (tid < cnt) {
      const int pt = base + tid;
      const bool match = (channels[pt] == c);
      unsigned long long mask = __ballot(match);
      int wcnt = __popcll(mask);
      int pos = 0;
      if (lane == 0 && wcnt) pos = atomicAdd(&l_cnt, wcnt);
      pos = __shfl(pos, 0);
      if (match) {
        int off = pos + __popcll(mask & ((1ull << lane) - 1ull));
        lx[off * 4 + 0] = x[pt * 3 + 0];
        lx[off * 4 + 1] = x[pt * 3 + 1];
        lx[off * 4 + 2] = x[pt * 3 + 2];
      }
    }
    __syncthreads();
    const int m = l_cnt;
    const float4* lx4 = (const float4*)lx;

    // waves stripe points; lane = t; software-pipelined point prefetch
    int j = wv;
    if (j < m) {
      float4 p = lx4[j];
      for (; ; ) {
        int jn = j + WAVES;
        float4 pn;
        if (jn < m) pn = lx4[jn];
        const float nh = p.x * v0 + p.y * v1 + p.z * v2;
        const float g  = fmaf(nh, invD, invD);     // (nh + 1) * 31.5
        const float gf = floorf(g);
        const float f  = g - gf;
        const int   fq = (int)(f * (float)TK);
        const int   lo = (int)gf - 1;
        const int   lc = min(max(lo, -PAD), RES);
        const uint4 tv = *(const uint4*)&tbl[fq << 2];
        unsigned* srow = srow0 + (lc + PAD);
        atomicAdd(&srow[0], tv.x);
        atomicAdd(&srow[1], tv.y);
        atomicAdd(&srow[2], tv.z);
        atomicAdd(&srow[3], tv.w);
        const int ci = min(max(lo + NB, 0), RES);
        atomicAdd(&hrow0[ci], 1u);
        if (jn >= m) break;
        j = jn;
        p = pn;
      }
    }
    __syncthreads();
  }

  // per-t inclusive prefix over r of hist, combine with window sums -> fin (reuses lx, stride 65)
  float* fin = lx;
  #pragma unroll
  for (int u2 = 0; u2 < 4; ++u2) {
    const int t = (wv << 2) | u2;
    unsigned h = hist[t * HSTR + lane];            // lane = r
    #pragma unroll
    for (int d = 1; d < 64; d <<= 1) {
      unsigned o = __shfl_up(h, (unsigned)d);
      if (lane >= d) h += o;
    }
    fin[lane * 65 + t] = (float)sig[t * SSTR + (lane + PAD)] * FPINV + (float)h;
  }
  __syncthreads();

  // block max-reduce + normalize + coalesced store
  float vals[4];
  float mx = 0.0f;
  #pragma unroll
  for (int k = 0; k < 4; ++k) {
    const int r = wv + k * 16;                     // flat = tid + k*1024 -> r = wv + 16k, t = lane
    vals[k] = fin[r * 65 + lane];
    mx = fmaxf(mx, vals[k]);
  }
  #pragma unroll
  for (int s = 32; s >= 1; s >>= 1) mx = fmaxf(mx, __shfl_xor(mx, s));
  if (lane == 0) wmax[wv] = mx;
  __syncthreads();
  if (tid == 0) {
    float m2 = wmax[0];
    #pragma unroll
    for (int i = 1; i < WAVES; ++i) m2 = fmaxf(m2, wmax[i]);
    s_scale = (m2 > 0.0f) ? 1.0f / m2 : 1.0f;
  }
  __syncthreads();
  const float sc = s_scale;
  float* o = out + (size_t)seg * (RES * T);
  #pragma unroll
  for (int k = 0; k < 4; ++k) o[tid + k * THREADS] = vals[k] * sc;
}

extern "C" void kernel_launch(void* const* d_in, const int* in_sizes, int n_in,
                              void* d_out, int out_size, void* d_ws, size_t ws_size,
                              hipStream_t stream) {
  const float* x        = (const float*)d_in[0];
  const float* v        = (const float*)d_in[1];
  const int*   index    = (const int*)d_in[2];
  const int*   channels = (const int*)d_in[3];
  float*       out      = (float*)d_out;
  const int N    = in_sizes[2];              // 32768
  const int nseg = out_size / (RES * T);     // 128

  hipLaunchKernelGGL(ect_main, dim3(nseg), dim3(THREADS), 0, stream,
                     x, v, index, channels, out, N);
}